// Round 10
// baseline (556.209 us; speedup 1.0000x reference)
//
#include <hip/hip_runtime.h>

typedef __attribute__((ext_vector_type(4))) float f32x4;
typedef __attribute__((ext_vector_type(8))) __bf16 bf16x8;
typedef __attribute__((ext_vector_type(8))) unsigned short us8;
typedef unsigned short u16;

#define SSILU_SCALE (1.0f / 0.6f)
#define INV_SQRT2 0.70710678118654752f

__device__ __forceinline__ u16 f2bf(float f) {
    __bf16 h = (__bf16)f;
    return __builtin_bit_cast(u16, h);
}
__device__ __forceinline__ float bf2f(u16 h) {
    union { unsigned int u; float f; } v; v.u = ((unsigned int)h) << 16;
    return v.f;
}
__device__ __forceinline__ float ssilu(float x) {
    float e = __expf(-x);
    float s = __builtin_amdgcn_rcpf(1.0f + e);
    return x * s * SSILU_SCALE;
}

// ---------------------------------------------------------------------------
// prep: (unchanged layouts)
//  WinF : W_in as B-fragments [kt20][w4][kk2][n4][lane64][8]
//  Wfrag: 4 resid matrices as [g][w4][kk8][n4][lane64][8]
// ---------------------------------------------------------------------------
__global__ __launch_bounds__(256) void prep_kernel(
    const float* __restrict__ Win, const float* __restrict__ W1a,
    const float* __restrict__ W1b, const float* __restrict__ W2a,
    const float* __restrict__ W2b, u16* __restrict__ WinF,
    u16* __restrict__ Wfrag, float* __restrict__ out, int outN) {
    int i = blockIdx.x * 256 + threadIdx.x;
    if (i < 327680) {
        int e = i & 7, lane = (i >> 3) & 63, n = (i >> 9) & 3;
        int kk = (i >> 11) & 1, w = (i >> 12) & 3, kt = i >> 14;
        int lo = lane & 15, hi = lane >> 4;
        int k = kt * 64 + kk * 32 + hi * 8 + e;
        int col = w * 64 + n * 16 + lo;
        WinF[i] = f2bf(Win[k * 256 + col]);
        return;
    }
    int j = i - 327680;
    if (j < 262144) {
        int g = j >> 16, r = j & 65535;
        int chunk = r >> 9, within = r & 511;
        int lane = within >> 3, e = within & 7;
        int w = chunk >> 5, kk = (chunk >> 2) & 7, n = chunk & 3;
        int lo = lane & 15, hi = lane >> 4;
        int col = w * 64 + n * 16 + lo;
        int k = kk * 32 + hi * 8 + e;
        const float* W = (g == 0) ? W1a : (g == 1) ? W1b : (g == 2) ? W2a : W2b;
        Wfrag[j] = f2bf(W[k * 256 + col]);
        return;
    }
    int z = j - 262144;
    if (z < outN) out[z] = 0.0f;
}

// ---------------------------------------------------------------------------
// phase-2 half-GEMM: 32 output rows (rows (row_off+m)*16+lo of buffer AB),
// 4 waves, wave owns 64 cols. B streams from L2, rolling 1-kk prefetch.
// ---------------------------------------------------------------------------
__device__ __forceinline__ void gemm_half(const char* AB, int row_off,
                                          const u16* __restrict__ Wg,
                                          int l, int lo, int hi, f32x4 acc[2][4]) {
#pragma unroll
    for (int m = 0; m < 2; m++)
#pragma unroll
        for (int n = 0; n < 4; n++) acc[m][n] = (f32x4){0.f, 0.f, 0.f, 0.f};
    bf16x8 bv[4], bvn[4];
#pragma unroll
    for (int n = 0; n < 4; n++)
        bv[n] = __builtin_bit_cast(bf16x8,
            *(const us8*)(Wg + (size_t)n * 512 + l * 8));
#pragma unroll
    for (int kk = 0; kk < 8; ++kk) {
        int kbyte = kk * 64 + hi * 16;
        bf16x8 af[2];
#pragma unroll
        for (int m = 0; m < 2; m++) {
            int r = (row_off + m) * 16 + lo;
            af[m] = __builtin_bit_cast(bf16x8,
                *(const us8*)(AB + r * 512 + (kbyte ^ ((r & 7) << 4))));
        }
        if (kk < 7) {
#pragma unroll
            for (int n = 0; n < 4; n++)
                bvn[n] = __builtin_bit_cast(bf16x8,
                    *(const us8*)(Wg + (size_t)((kk + 1) * 4 + n) * 512 + l * 8));
        }
#pragma unroll
        for (int m = 0; m < 2; m++)
#pragma unroll
            for (int n = 0; n < 4; n++)
                acc[m][n] = __builtin_amdgcn_mfma_f32_16x16x32_bf16(
                    af[m], bv[n], acc[m][n], 0, 0, 0);
        if (kk < 7) {
#pragma unroll
            for (int n = 0; n < 4; n++) bv[n] = bvn[n];
        }
    }
}

// ---------------------------------------------------------------------------
// fused: 64 edge-rows per block, 4 waves (wave w -> cols 64w..64w+63).
// LDS ~49KB -> 3 independent blocks/CU. Phase 1: R6's 64-row pipeline with
// rolling per-kk B prefetch (low VGPR). Phase 2: residual stack with
// M-row-split half-GEMMs sharing a 16KB t1 buffer.
// ---------------------------------------------------------------------------
__global__ __launch_bounds__(256, 3) void fused_kernel(
    const float* __restrict__ A, const u16* __restrict__ WinF,
    const u16* __restrict__ Wfrag, const float* __restrict__ Wout,
    const float* __restrict__ evec, const int* __restrict__ eidx,
    float* __restrict__ out) {
    __shared__ u16 xb[64 * 256];   // 32KB swizzled x tile (512B rows)
    __shared__ u16 tb[32 * 256];   // 16KB t1 half-buffer; A dbuf in phase 1
    __shared__ float fpart[4][64];
    const int t = threadIdx.x, w = t >> 6, l = t & 63;
    const int lo = l & 15, hi = l >> 4;
    const int swz = (lo & 7) << 4;
    const long rowbase = (long)blockIdx.x * 64;
    char* xbB = (char*)xb;
    char* tbB = (char*)tb;
    char* As0 = tbB;               // 2 x 8KB A dbuf aliased in tb (phase 1 only)
    char* As1 = tbB + 8192;

    f32x4 acc[4][4];
#pragma unroll
    for (int m = 0; m < 4; m++)
#pragma unroll
        for (int n = 0; n < 4; n++) acc[m][n] = (f32x4){0.f, 0.f, 0.f, 0.f};

    // ---------------- phase 1: x = ssilu(x_cat @ W_in) ----------------
    float4 va[2][2];
    auto LOADA = [&](int kb) {
#pragma unroll
        for (int c = 0; c < 2; ++c) {
            int idx = t + c * 256;
            int r = idx >> 3, k8 = (idx & 7) * 8;
            const float* s = A + (rowbase + r) * 1280 + kb + k8;
            va[c][0] = *(const float4*)s;
            va[c][1] = *(const float4*)(s + 4);
        }
    };
    auto WRITEA = [&](char* dst) {
#pragma unroll
        for (int c = 0; c < 2; ++c) {
            int idx = t + c * 256;
            int r = idx >> 3, k8 = (idx & 7) * 8;
            us8 p;
            p[0] = f2bf(va[c][0].x); p[1] = f2bf(va[c][0].y);
            p[2] = f2bf(va[c][0].z); p[3] = f2bf(va[c][0].w);
            p[4] = f2bf(va[c][1].x); p[5] = f2bf(va[c][1].y);
            p[6] = f2bf(va[c][1].z); p[7] = f2bf(va[c][1].w);
            *(us8*)(dst + r * 128 + ((k8 * 2) ^ ((r & 7) << 4))) = p;
        }
    };
    const u16* WinFw = WinF + w * 4096 + l * 8;
    auto LOADB = [&](int kt, int kk, bf16x8 (&b)[4]) {
        const u16* base = WinFw + kt * 16384 + kk * 2048;
#pragma unroll
        for (int n = 0; n < 4; ++n)
            b[n] = __builtin_bit_cast(bf16x8, *(const us8*)(base + n * 512));
    };
    auto MFMA_KK = [&](const char* AB, int kk, const bf16x8 (&bc)[4]) {
        int kbyte = kk * 64 + hi * 16;
        bf16x8 af[4];
#pragma unroll
        for (int m = 0; m < 4; m++) {
            int r = m * 16 + lo;
            af[m] = __builtin_bit_cast(bf16x8,
                *(const us8*)(AB + r * 128 + (kbyte ^ swz)));
        }
#pragma unroll
        for (int m = 0; m < 4; m++)
#pragma unroll
            for (int n = 0; n < 4; n++)
                acc[m][n] = __builtin_amdgcn_mfma_f32_16x16x32_bf16(
                    af[m], bc[n], acc[m][n], 0, 0, 0);
    };
    auto FENCE = [&]() {
        asm volatile("s_waitcnt lgkmcnt(0)" ::: "memory");
        __builtin_amdgcn_sched_barrier(0);
        __builtin_amdgcn_s_barrier();
    };

    bf16x8 bc[4], bn[4];

    // prologue: As0 <- A(0); va <- A(1); bc <- B(0,0)
    LOADA(0);
    WRITEA(As0);
    LOADB(0, 0, bc);
    LOADA(64);
    FENCE();

    auto STEP = [&](int kt, const char* AScur, char* ASnxt) {
        const bool more = (kt < 19);
        LOADB(kt, 1, bn);                    // B(kt,1), used ~16 MFMA later
        MFMA_KK(AScur, 0, bc);
        if (more) LOADB(kt + 1, 0, bc);      // B(kt+1,0) for next step
        MFMA_KK(AScur, 1, bn);
        if (more) WRITEA(ASnxt);             // stage A(kt+1) (waits its loads)
        if (kt <= 17) LOADA((kt + 2) * 64);  // prefetch A(kt+2)
        FENCE();
    };

    for (int i = 0; i < 10; ++i) {
        STEP(2 * i,     As0, As1);
        STEP(2 * i + 1, As1, As0);
    }

    // epilogue: x = ssilu(acc) -> xb (swizzled); tb's A-staging role ends
#pragma unroll
    for (int m = 0; m < 4; m++)
#pragma unroll
        for (int n = 0; n < 4; n++)
#pragma unroll
            for (int j = 0; j < 4; j++) {
                int r = m * 16 + hi * 4 + j;
                int cc = w * 64 + n * 16 + lo;
                *(u16*)(xbB + r * 512 + ((cc * 2) ^ ((r & 7) << 4))) =
                    f2bf(ssilu(acc[m][n][j]));
            }
    __syncthreads();

    // ---------------- phase 2: residual stack, M-row-split halves ----------
    const u16* Wfw = Wfrag + w * 16384;   // lane offset added inside gemm_half
    f32x4 a2[2][4];

#pragma unroll
    for (int gp = 0; gp < 2; ++gp) {
        const u16* Wa = Wfw + (size_t)(gp * 2)     * 65536;
        const u16* Wb = Wfw + (size_t)(gp * 2 + 1) * 65536;
#pragma unroll
        for (int h = 0; h < 2; ++h) {
            // Ga half h: t1[32h..32h+31] = ssilu(x @ Wa) -> tb (local rows)
            gemm_half(xbB, 2 * h, Wa, l, lo, hi, a2);
#pragma unroll
            for (int m = 0; m < 2; m++)
#pragma unroll
                for (int n = 0; n < 4; n++)
#pragma unroll
                    for (int j = 0; j < 4; j++) {
                        int r = m * 16 + hi * 4 + j;            // local row
                        int cc = w * 64 + n * 16 + lo;
                        *(u16*)(tbB + r * 512 + ((cc * 2) ^ ((r & 7) << 4))) =
                            f2bf(ssilu(a2[m][n][j]));
                    }
            __syncthreads();

            // Gb half h
            gemm_half(tbB, 0, Wb, l, lo, hi, a2);
            if (gp == 0) {
                // x[32h..] = (x + ssilu(t1 @ Wb)) * INV_SQRT2 -> xb
#pragma unroll
                for (int m = 0; m < 2; m++)
#pragma unroll
                    for (int n = 0; n < 4; n++)
#pragma unroll
                        for (int j = 0; j < 4; j++) {
                            int rg = (2 * h + m) * 16 + hi * 4 + j;
                            int cc = w * 64 + n * 16 + lo;
                            char* p = xbB + rg * 512 + ((cc * 2) ^ ((rg & 7) << 4));
                            float xn = (bf2f(*(u16*)p) + ssilu(a2[m][n][j])) * INV_SQRT2;
                            *(u16*)p = f2bf(xn);
                        }
            } else {
                // final: x_f = (x + ssilu(t1 @ Wb)) * INV_SQRT2; dot W_out
                float wo[4];
#pragma unroll
                for (int n = 0; n < 4; n++) wo[n] = Wout[w * 64 + n * 16 + lo];
                float part[2][4];
#pragma unroll
                for (int m = 0; m < 2; m++)
#pragma unroll
                    for (int j = 0; j < 4; j++) part[m][j] = 0.f;
#pragma unroll
                for (int m = 0; m < 2; m++)
#pragma unroll
                    for (int n = 0; n < 4; n++)
#pragma unroll
                        for (int j = 0; j < 4; j++) {
                            int rg = (2 * h + m) * 16 + hi * 4 + j;
                            int cc = w * 64 + n * 16 + lo;
                            const char* p = xbB + rg * 512 + ((cc * 2) ^ ((rg & 7) << 4));
                            float xf = (bf2f(*(const u16*)p) + ssilu(a2[m][n][j])) * INV_SQRT2;
                            part[m][j] += xf * wo[n];
                        }
#pragma unroll
                for (int m = 0; m < 2; m++)
#pragma unroll
                    for (int j = 0; j < 4; j++) {
                        float v = part[m][j];
                        v += __shfl_xor(v, 1);
                        v += __shfl_xor(v, 2);
                        v += __shfl_xor(v, 4);
                        v += __shfl_xor(v, 8);
                        if (lo == 0) fpart[w][(2 * h + m) * 16 + hi * 4 + j] = v;
                    }
            }
            __syncthreads();
        }
    }

    if (t < 64) {
        int r = t;
        float F = fpart[0][r] + fpart[1][r] + fpart[2][r] + fpart[3][r];
        long e = rowbase + r;
        float vx = evec[e * 3 + 0], vy = evec[e * 3 + 1], vz = evec[e * 3 + 2];
        int a = eidx[e];
        atomicAdd(&out[a * 3 + 0], F * vx);
        atomicAdd(&out[a * 3 + 1], F * vy);
        atomicAdd(&out[a * 3 + 2], F * vz);
    }
}

extern "C" void kernel_launch(void* const* d_in, const int* in_sizes, int n_in,
                              void* d_out, int out_size, void* d_ws, size_t ws_size,
                              hipStream_t stream) {
    const float* x_cat = (const float*)d_in[0];
    const float* evec  = (const float*)d_in[1];
    const int*   eidx  = (const int*)d_in[2];
    const float* Win   = (const float*)d_in[3];
    const float* W1a   = (const float*)d_in[4];
    const float* W1b   = (const float*)d_in[5];
    const float* W2a   = (const float*)d_in[6];
    const float* W2b   = (const float*)d_in[7];
    const float* Wout  = (const float*)d_in[8];
    float* out = (float*)d_out;
    const int E = in_sizes[1] / 3;   // 200000

    u16* WinF  = (u16*)d_ws;          // 327680 elems
    u16* Wfrag = WinF + 327680;       // 262144 elems

    int prepN = 327680 + 262144 + out_size;
    prep_kernel<<<(prepN + 255) / 256, 256, 0, stream>>>(
        Win, W1a, W1b, W2a, W2b, WinF, Wfrag, out, out_size);
    fused_kernel<<<E / 64, 256, 0, stream>>>(
        x_cat, WinF, Wfrag, Wout, evec, eidx, out);
}

// Round 11
// 390.420 us; speedup vs baseline: 1.4246x; 1.4246x over previous
//
#include <hip/hip_runtime.h>

typedef __attribute__((ext_vector_type(4))) float f32x4;
typedef __attribute__((ext_vector_type(8))) __bf16 bf16x8;
typedef __attribute__((ext_vector_type(8))) unsigned short us8;
typedef unsigned short u16;

#define SSILU_SCALE (1.0f / 0.6f)
#define INV_SQRT2 0.70710678118654752f

__device__ __forceinline__ u16 f2bf(float f) {
    __bf16 h = (__bf16)f;
    return __builtin_bit_cast(u16, h);
}
__device__ __forceinline__ float bf2f(u16 h) {
    union { unsigned int u; float f; } v; v.u = ((unsigned int)h) << 16;
    return v.f;
}
__device__ __forceinline__ float ssilu(float x) {
    float e = __expf(-x);
    float s = __builtin_amdgcn_rcpf(1.0f + e);
    return x * s * SSILU_SCALE;
}

// ---------------------------------------------------------------------------
// prep: (unchanged layouts)
//  WinF : W_in as B-fragments [kt20][w4][kk2][n4][lane64][8]
//  Wfrag: 4 resid matrices as [g][w4][kk8][n4][lane64][8]
// ---------------------------------------------------------------------------
__global__ __launch_bounds__(256) void prep_kernel(
    const float* __restrict__ Win, const float* __restrict__ W1a,
    const float* __restrict__ W1b, const float* __restrict__ W2a,
    const float* __restrict__ W2b, u16* __restrict__ WinF,
    u16* __restrict__ Wfrag, float* __restrict__ out, int outN) {
    int i = blockIdx.x * 256 + threadIdx.x;
    if (i < 327680) {
        int e = i & 7, lane = (i >> 3) & 63, n = (i >> 9) & 3;
        int kk = (i >> 11) & 1, w = (i >> 12) & 3, kt = i >> 14;
        int lo = lane & 15, hi = lane >> 4;
        int k = kt * 64 + kk * 32 + hi * 8 + e;
        int col = w * 64 + n * 16 + lo;
        WinF[i] = f2bf(Win[k * 256 + col]);
        return;
    }
    int j = i - 327680;
    if (j < 262144) {
        int g = j >> 16, r = j & 65535;
        int chunk = r >> 9, within = r & 511;
        int lane = within >> 3, e = within & 7;
        int w = chunk >> 5, kk = (chunk >> 2) & 7, n = chunk & 3;
        int lo = lane & 15, hi = lane >> 4;
        int col = w * 64 + n * 16 + lo;
        int k = kk * 32 + hi * 8 + e;
        const float* W = (g == 0) ? W1a : (g == 1) ? W1b : (g == 2) ? W2a : W2b;
        Wfrag[j] = f2bf(W[k * 256 + col]);
        return;
    }
    int z = j - 262144;
    if (z < outN) out[z] = 0.0f;
}

// ---------------------------------------------------------------------------
// phase-2 GEMM (R6 verbatim): 64x256 tile, 4 waves, wave owns 64 cols.
// B streams coalesced from Wfrag (internal l*8 lane offset).
// ---------------------------------------------------------------------------
__device__ __forceinline__ void gemm_lds(const char* AB, const u16* __restrict__ Wfw,
                                         int l, int lo, int hi, f32x4 acc[4][4]) {
#pragma unroll
    for (int m = 0; m < 4; m++)
#pragma unroll
        for (int n = 0; n < 4; n++) acc[m][n] = (f32x4){0.f, 0.f, 0.f, 0.f};
    bf16x8 bv[4], bvn[4];
#pragma unroll
    for (int n = 0; n < 4; n++)
        bv[n] = __builtin_bit_cast(bf16x8,
            *(const us8*)(Wfw + (size_t)n * 512 + l * 8));
#pragma unroll
    for (int kk = 0; kk < 8; ++kk) {
        int kbyte = kk * 64 + hi * 16;
        bf16x8 af[4];
#pragma unroll
        for (int m = 0; m < 4; m++) {
            int r = m * 16 + lo;
            af[m] = __builtin_bit_cast(bf16x8,
                *(const us8*)(AB + r * 512 + (kbyte ^ ((r & 7) << 4))));
        }
        if (kk < 7) {
#pragma unroll
            for (int n = 0; n < 4; n++)
                bvn[n] = __builtin_bit_cast(bf16x8,
                    *(const us8*)(Wfw + (size_t)((kk + 1) * 4 + n) * 512 + l * 8));
        }
#pragma unroll
        for (int m = 0; m < 4; m++)
#pragma unroll
            for (int n = 0; n < 4; n++)
                acc[m][n] = __builtin_amdgcn_mfma_f32_16x16x32_bf16(
                    af[m], bv[n], acc[m][n], 0, 0, 0);
        if (kk < 7) {
#pragma unroll
            for (int n = 0; n < 4; n++) bv[n] = bvn[n];
        }
    }
}

// ---------------------------------------------------------------------------
// fused: 64 edge-rows, 4 waves (wave w -> cols 64w..64w+63). 65KB LDS,
// 2 blocks/CU. Phase 1: BK=128 steps — 64 MFMA/barrier, 10 barriers,
// A 1-step reg prefetch into 2x16KB LDS dbuf (aliased in tb, 256B rows),
// B half-step-rolling bc/bn (32-MFMA cover each). Phase 2: R6 verbatim.
// ---------------------------------------------------------------------------
__global__ __launch_bounds__(256, 2) void fused_kernel(
    const float* __restrict__ A, const u16* __restrict__ WinF,
    const u16* __restrict__ Wfrag, const float* __restrict__ Wout,
    const float* __restrict__ evec, const int* __restrict__ eidx,
    float* __restrict__ out) {
    __shared__ u16 xb[64 * 256];   // 32KB swizzled x tile (512B rows)
    __shared__ u16 tb[64 * 256];   // 32KB temp; = 2x16KB A dbuf in phase 1
    __shared__ float fpart[4][64];
    const int t = threadIdx.x, w = t >> 6, l = t & 63;
    const int lo = l & 15, hi = l >> 4;
    const int swz = (lo & 7) << 4;
    const long rowbase = (long)blockIdx.x * 64;
    char* xbB = (char*)xb;
    char* tbB = (char*)tb;
    char* As0 = tbB;                // 16KB: 64 rows x 256B (128 k bf16)
    char* As1 = tbB + 16384;

    f32x4 acc[4][4];
#pragma unroll
    for (int m = 0; m < 4; m++)
#pragma unroll
        for (int n = 0; n < 4; n++) acc[m][n] = (f32x4){0.f, 0.f, 0.f, 0.f};

    // ---------------- phase 1: x = ssilu(x_cat @ W_in), BK=128 ----------------
    float4 va[4][2];
    auto LOADA = [&](int kb) {
#pragma unroll
        for (int c = 0; c < 4; ++c) {
            int idx = t + c * 256;
            int r = idx >> 4, k8 = (idx & 15) * 8;
            const float* s = A + (rowbase + r) * 1280 + kb + k8;
            va[c][0] = *(const float4*)s;
            va[c][1] = *(const float4*)(s + 4);
        }
    };
    auto WRITEA = [&](char* dst) {
#pragma unroll
        for (int c = 0; c < 4; ++c) {
            int idx = t + c * 256;
            int r = idx >> 4, k8 = (idx & 15) * 8;
            us8 p;
            p[0] = f2bf(va[c][0].x); p[1] = f2bf(va[c][0].y);
            p[2] = f2bf(va[c][0].z); p[3] = f2bf(va[c][0].w);
            p[4] = f2bf(va[c][1].x); p[5] = f2bf(va[c][1].y);
            p[6] = f2bf(va[c][1].z); p[7] = f2bf(va[c][1].w);
            *(us8*)(dst + r * 256 + ((k8 * 2) ^ ((r & 7) << 4))) = p;
        }
    };
    const u16* WinFw = WinF + w * 4096 + l * 8;
    // b[8] = one 64-K half (tile kt): kkL in {0,1} x n in 0..3
    auto LOADB = [&](int kt, bf16x8 (&b)[8]) {
        const u16* base = WinFw + kt * 16384;
#pragma unroll
        for (int kkL = 0; kkL < 2; ++kkL)
#pragma unroll
            for (int n = 0; n < 4; ++n)
                b[kkL * 4 + n] = __builtin_bit_cast(bf16x8,
                    *(const us8*)(base + kkL * 2048 + n * 512));
    };
    // half = 0: kk 0,1 ; half = 1: kk 2,3  (256B A rows)
    auto MFMA_HALF = [&](const char* AB, int half, const bf16x8 (&b)[8]) {
#pragma unroll
        for (int kkL = 0; kkL < 2; ++kkL) {
            int kbyte = (half * 2 + kkL) * 64 + hi * 16;
            bf16x8 af[4];
#pragma unroll
            for (int m = 0; m < 4; m++) {
                int r = m * 16 + lo;
                af[m] = __builtin_bit_cast(bf16x8,
                    *(const us8*)(AB + r * 256 + (kbyte ^ swz)));
            }
#pragma unroll
            for (int m = 0; m < 4; m++)
#pragma unroll
                for (int n = 0; n < 4; n++)
                    acc[m][n] = __builtin_amdgcn_mfma_f32_16x16x32_bf16(
                        af[m], b[kkL * 4 + n], acc[m][n], 0, 0, 0);
        }
    };
    auto FENCE = [&]() {
        asm volatile("s_waitcnt lgkmcnt(0)" ::: "memory");
        __builtin_amdgcn_sched_barrier(0);
        __builtin_amdgcn_s_barrier();
    };

    bf16x8 bc[8], bn[8];

    // prologue: As0 <- A(step 0); va <- A(step 1); bc <- B(tile 0) = kk01
    LOADA(0);
    WRITEA(As0);
    LOADB(0, bc);
    LOADA(128);
    FENCE();

    auto STEP = [&](int s, const char* AScur, char* ASnxt) {
        const bool more = (s < 9);
        LOADB(2 * s + 1, bn);                 // this step's kk23 (32-MFMA cover)
        __builtin_amdgcn_sched_barrier(0);
        MFMA_HALF(AScur, 0, bc);              // 32 MFMA
        if (more) LOADB(2 * s + 2, bc);       // next step's kk01
        MFMA_HALF(AScur, 1, bn);              // 32 MFMA
        if (more) WRITEA(ASnxt);              // stage A(s+1) (waits its loads)
        if (s <= 7) LOADA((s + 2) * 128);     // prefetch A(s+2)
        FENCE();
    };

    for (int i = 0; i < 5; ++i) {
        STEP(2 * i,     As0, As1);
        STEP(2 * i + 1, As1, As0);
    }

    // epilogue: x = ssilu(acc) -> xb (swizzled); tb's A-staging role ends
#pragma unroll
    for (int m = 0; m < 4; m++)
#pragma unroll
        for (int n = 0; n < 4; n++)
#pragma unroll
            for (int j = 0; j < 4; j++) {
                int r = m * 16 + hi * 4 + j;
                int cc = w * 64 + n * 16 + lo;
                *(u16*)(xbB + r * 512 + ((cc * 2) ^ ((r & 7) << 4))) =
                    f2bf(ssilu(acc[m][n][j]));
            }
    __syncthreads();

    // ---------------- phase 2: residual stack (R6 verbatim) ----------------
    const u16* Wfw = Wfrag + w * 16384;   // lane offset added inside gemm_lds

    // G1: t1 = ssilu(x @ W1a) -> tb
    gemm_lds(xbB, Wfw + 0 * 65536, l, lo, hi, acc);
#pragma unroll
    for (int m = 0; m < 4; m++)
#pragma unroll
        for (int n = 0; n < 4; n++)
#pragma unroll
            for (int j = 0; j < 4; j++) {
                int r = m * 16 + hi * 4 + j;
                int cc = w * 64 + n * 16 + lo;
                *(u16*)(tbB + r * 512 + ((cc * 2) ^ ((r & 7) << 4))) =
                    f2bf(ssilu(acc[m][n][j]));
            }
    __syncthreads();

    // G2: x = (x + ssilu(t1 @ W1b)) * INV_SQRT2 -> xb
    gemm_lds(tbB, Wfw + 1 * 65536, l, lo, hi, acc);
#pragma unroll
    for (int m = 0; m < 4; m++)
#pragma unroll
        for (int n = 0; n < 4; n++)
#pragma unroll
            for (int j = 0; j < 4; j++) {
                int r = m * 16 + hi * 4 + j;
                int cc = w * 64 + n * 16 + lo;
                char* p = xbB + r * 512 + ((cc * 2) ^ ((r & 7) << 4));
                float xn = (bf2f(*(u16*)p) + ssilu(acc[m][n][j])) * INV_SQRT2;
                *(u16*)p = f2bf(xn);
            }
    __syncthreads();

    // G3: t1 = ssilu(x @ W2a) -> tb
    gemm_lds(xbB, Wfw + 2 * 65536, l, lo, hi, acc);
#pragma unroll
    for (int m = 0; m < 4; m++)
#pragma unroll
        for (int n = 0; n < 4; n++)
#pragma unroll
            for (int j = 0; j < 4; j++) {
                int r = m * 16 + hi * 4 + j;
                int cc = w * 64 + n * 16 + lo;
                *(u16*)(tbB + r * 512 + ((cc * 2) ^ ((r & 7) << 4))) =
                    f2bf(ssilu(acc[m][n][j]));
            }
    __syncthreads();

    // G4: x_final = (x + ssilu(t1 @ W2b)) * INV_SQRT2, fp32 in regs
    gemm_lds(tbB, Wfw + 3 * 65536, l, lo, hi, acc);
    float wo[4];
#pragma unroll
    for (int n = 0; n < 4; n++) wo[n] = Wout[w * 64 + n * 16 + lo];

    float part[4][4];
#pragma unroll
    for (int m = 0; m < 4; m++)
#pragma unroll
        for (int j = 0; j < 4; j++) part[m][j] = 0.f;
#pragma unroll
    for (int m = 0; m < 4; m++)
#pragma unroll
        for (int n = 0; n < 4; n++)
#pragma unroll
            for (int j = 0; j < 4; j++) {
                int r = m * 16 + hi * 4 + j;
                int cc = w * 64 + n * 16 + lo;
                const char* p = xbB + r * 512 + ((cc * 2) ^ ((r & 7) << 4));
                float xf = (bf2f(*(const u16*)p) + ssilu(acc[m][n][j])) * INV_SQRT2;
                part[m][j] += xf * wo[n];
            }
#pragma unroll
    for (int m = 0; m < 4; m++)
#pragma unroll
        for (int j = 0; j < 4; j++) {
            float v = part[m][j];
            v += __shfl_xor(v, 1);
            v += __shfl_xor(v, 2);
            v += __shfl_xor(v, 4);
            v += __shfl_xor(v, 8);
            if (lo == 0) fpart[w][m * 16 + hi * 4 + j] = v;
        }
    __syncthreads();

    if (t < 64) {
        int r = t;
        float F = fpart[0][r] + fpart[1][r] + fpart[2][r] + fpart[3][r];
        long e = rowbase + r;
        float vx = evec[e * 3 + 0], vy = evec[e * 3 + 1], vz = evec[e * 3 + 2];
        int a = eidx[e];
        atomicAdd(&out[a * 3 + 0], F * vx);
        atomicAdd(&out[a * 3 + 1], F * vy);
        atomicAdd(&out[a * 3 + 2], F * vz);
    }
}

extern "C" void kernel_launch(void* const* d_in, const int* in_sizes, int n_in,
                              void* d_out, int out_size, void* d_ws, size_t ws_size,
                              hipStream_t stream) {
    const float* x_cat = (const float*)d_in[0];
    const float* evec  = (const float*)d_in[1];
    const int*   eidx  = (const int*)d_in[2];
    const float* Win   = (const float*)d_in[3];
    const float* W1a   = (const float*)d_in[4];
    const float* W1b   = (const float*)d_in[5];
    const float* W2a   = (const float*)d_in[6];
    const float* W2b   = (const float*)d_in[7];
    const float* Wout  = (const float*)d_in[8];
    float* out = (float*)d_out;
    const int E = in_sizes[1] / 3;   // 200000

    u16* WinF  = (u16*)d_ws;          // 327680 elems
    u16* Wfrag = WinF + 327680;       // 262144 elems

    int prepN = 327680 + 262144 + out_size;
    prep_kernel<<<(prepN + 255) / 256, 256, 0, stream>>>(
        Win, W1a, W1b, W2a, W2b, WinF, Wfrag, out, out_size);
    fused_kernel<<<E / 64, 256, 0, stream>>>(
        x_cat, WinF, Wfrag, Wout, evec, eidx, out);
}